// Round 3
// baseline (76.987 us; speedup 1.0000x reference)
//
#include <hip/hip_runtime.h>
#include <math.h>

// ROI max pooling, TF-style bin mapping (see reference):
//   hs = (int)(H*roi[0]) (truncate), sh = max((he-hs)/7, 1)
//   bin i<6 rows: [hs+i*sh, min(hs+(i+1)*sh, he));  bin 6: [hs+6*sh, he)
// Shapes fixed by setup_inputs(): fm (2,50,50,256) f32, rois (2,100,4) f32,
// out (2,100,7,7,256) f32.
//
// R3: fixed-overhead fix — R1/R2 fit shows ~21 us cost invariant to per-wave
// latency; suspect per-workgroup dispatch/setup of 9800 single-wave blocks.
// Now one block per (roi, row-bin i): 1400 blocks x 128 threads (2 waves).
// Wave 0 -> column-bins j=0..3, wave 1 -> j=4..6. ROI descriptor + bounds
// computed once per wave, amortized over ~7x more loads. Inner loop keeps
// the 8-deep MLP chunk structure (8 outstanding float4 loads per waitcnt).
// Lane c holds channels 4c..4c+3 (64 lanes x float4 = 256 ch = 1 KiB/wave
// per position, ideal coalescing).

#define PH 7
#define PW 7
#define B_ 2
#define H_ 50
#define W_ 50
#define C_ 256
#define R_ 100

#define CHUNK 8

__global__ __launch_bounds__(128) void ROIPoolingLayer_33071248179308_kernel(
    const float* __restrict__ fm,    // (B,H,W,C)
    const float* __restrict__ rois,  // (B,R,4)
    float* __restrict__ out)         // (B,R,PH,PW,C)
{
    const int block  = blockIdx.x;        // roiIdx*7 + i
    const int i      = block % PH;
    const int roiIdx = block / PH;        // b*R + r
    const int b      = roiIdx / R_;
    const int wave   = threadIdx.x >> 6;  // 0 or 1
    const int lane   = threadIdx.x & 63;
    const int c      = lane * 4;          // 64 lanes x 4 ch = 256 = C_

    // One 16B load for the whole ROI descriptor (wave-uniform address -> s_load).
    const float4 roi = *(const float4*)(rois + (size_t)roiIdx * 4);

    // Truncating casts match jnp astype(int32) for non-negative values.
    const int hs = (int)((float)H_ * roi.x);
    const int ws = (int)((float)W_ * roi.y);
    const int he = (int)((float)H_ * roi.z);
    const int we = (int)((float)W_ * roi.w);
    const int sh = max((he - hs) / PH, 1);
    const int sw = max((we - ws) / PW, 1);

    const int y0 = hs + i * sh;
    const int y1 = (i == PH - 1) ? he : min(hs + (i + 1) * sh, he);
    const int bh = y1 - y0;

    const float* fmb = fm + ((size_t)b * H_ * W_ + (size_t)y0 * W_) * C_ + c;
    float* outb = out + ((size_t)roiIdx * PH + i) * PW * C_ + c;

    const int jbeg = wave ? 4 : 0;
    const int jend = wave ? PW : 4;

    for (int j = jbeg; j < jend; ++j) {
        const int x0 = ws + j * sw;
        const int x1 = (j == PW - 1) ? we : min(ws + (j + 1) * sw, we);
        const int bw = x1 - x0;
        int n = (bw > 0 && bh > 0) ? bh * bw : 0;

        float4 m = make_float4(-INFINITY, -INFINITY, -INFINITY, -INFINITY);

        // Incremental position walker over the bin, row-major.
        int x = x0;
        const float* p = fmb + (size_t)x0 * C_;
        const ptrdiff_t row_skip = (ptrdiff_t)(W_ - bw) * C_;

        while (n > 0) {
            const int take = (n < CHUNK) ? n : CHUNK;
            float4 buf[CHUNK];
#pragma unroll
            for (int t = 0; t < CHUNK; ++t) {
                if (t < take) {
                    buf[t] = *(const float4*)p;   // back-to-back: 8 in flight
                    p += C_;
                    if (++x == x1) { x = x0; p += row_skip; }
                }
            }
#pragma unroll
            for (int t = 0; t < CHUNK; ++t) {
                if (t < take) {
                    m.x = fmaxf(m.x, buf[t].x);
                    m.y = fmaxf(m.y, buf[t].y);
                    m.z = fmaxf(m.z, buf[t].z);
                    m.w = fmaxf(m.w, buf[t].w);
                }
            }
            n -= take;
        }

        *(float4*)(outb + (size_t)j * C_) = m;
    }
}

extern "C" void kernel_launch(void* const* d_in, const int* in_sizes, int n_in,
                              void* d_out, int out_size, void* d_ws, size_t ws_size,
                              hipStream_t stream) {
    const float* fm   = (const float*)d_in[0];
    const float* rois = (const float*)d_in[1];
    float* out        = (float*)d_out;

    const int nblocks = B_ * R_ * PH;  // 1400 blocks x 128 threads (2 waves)
    ROIPoolingLayer_33071248179308_kernel<<<nblocks, 128, 0, stream>>>(fm, rois, out);
}

// Round 5
// 68.458 us; speedup vs baseline: 1.1246x; 1.1246x over previous
//
#include <hip/hip_runtime.h>
#include <math.h>

// ROI max pooling, TF-style bin mapping (see reference):
//   hs = (int)(H*roi[0]) (truncate), sh = max((he-hs)/7, 1)
//   bin i<6 rows: [hs+i*sh, min(hs+(i+1)*sh, he));  bin 6: [hs+6*sh, he)
// Shapes fixed: fm (2,50,50,256) f32, rois (2,100,4) f32, out (2,100,7,7,256) f32.
//
// Journal: R2 (9800 single-wave blocks, CHUNK=8) = best, 68.4us total.
// R3 (2800 waves, 3.5x longer chains) REGRESSED to 77.0 -> latency-bound,
// TLP is king; keep 9800 short-chain waves.
// R4: same wave->cell mapping as R2, repackaged 4 waves/block (2450 blocks)
// + CHUNK=16 so a typical bin (<=16 positions) completes in ONE waitcnt
// round, and nontemporal output stores so the 10 MB streamed output doesn't
// evict the 2.56 MB feature map from L2. R4a: fix nontemporal store type
// (builtin requires native ext_vector_type, not HIP_vector_type).

#define PH 7
#define PW 7
#define B_ 2
#define H_ 50
#define W_ 50
#define C_ 256
#define R_ 100

#define CHUNK 16

typedef float nfloat4 __attribute__((ext_vector_type(4)));

__global__ __launch_bounds__(256) void ROIPoolingLayer_33071248179308_kernel(
    const float* __restrict__ fm,    // (B,H,W,C)
    const float* __restrict__ rois,  // (B,R,4)
    float* __restrict__ out)         // (B,R,PH,PW,C)
{
    const int wave = threadIdx.x >> 6;            // 4 waves per block
    const int lane = threadIdx.x & 63;
    const int cell = blockIdx.x * 4 + wave;       // 0..9799: roiIdx*49 + bin
    const int bin  = cell % (PH * PW);
    const int roiIdx = cell / (PH * PW);          // b*R + r
    const int b    = roiIdx / R_;
    const int i    = bin / PW;
    const int j    = bin % PW;
    const int c    = lane * 4;                    // 64 lanes x float4 = 256 ch

    // One 16B load for the whole ROI descriptor (wave-uniform -> s_load).
    const float4 roi = *(const float4*)(rois + (size_t)roiIdx * 4);

    // Truncating casts match jnp astype(int32) for non-negative values.
    const int hs = (int)((float)H_ * roi.x);
    const int ws = (int)((float)W_ * roi.y);
    const int he = (int)((float)H_ * roi.z);
    const int we = (int)((float)W_ * roi.w);
    const int sh = max((he - hs) / PH, 1);
    const int sw = max((we - ws) / PW, 1);

    const int y0 = hs + i * sh;
    const int y1 = (i == PH - 1) ? he : min(hs + (i + 1) * sh, he);
    const int x0 = ws + j * sw;
    const int x1 = (j == PW - 1) ? we : min(ws + (j + 1) * sw, we);

    const int bw = x1 - x0;
    const int bh = y1 - y0;
    int n = (bw > 0 && bh > 0) ? bh * bw : 0;

    float4 m = make_float4(-INFINITY, -INFINITY, -INFINITY, -INFINITY);

    // Incremental position walker over the bin, row-major.
    int x = x0;
    const float* p = fm + ((size_t)b * H_ * W_ + (size_t)y0 * W_ + x0) * C_ + c;
    const ptrdiff_t row_skip = (ptrdiff_t)(W_ - bw) * C_;

    while (n > 0) {
        const int take = (n < CHUNK) ? n : CHUNK;
        float4 buf[CHUNK];
#pragma unroll
        for (int t = 0; t < CHUNK; ++t) {
            if (t < take) {
                buf[t] = *(const float4*)p;   // back-to-back: up to 16 in flight
                p += C_;
                if (++x == x1) { x = x0; p += row_skip; }
            }
        }
#pragma unroll
        for (int t = 0; t < CHUNK; ++t) {
            if (t < take) {
                m.x = fmaxf(m.x, buf[t].x);
                m.y = fmaxf(m.y, buf[t].y);
                m.z = fmaxf(m.z, buf[t].z);
                m.w = fmaxf(m.w, buf[t].w);
            }
        }
        n -= take;
    }

    // Nontemporal: output is streamed (never re-read) — don't evict fm from L2.
    nfloat4 mv;
    mv.x = m.x; mv.y = m.y; mv.z = m.z; mv.w = m.w;
    nfloat4* dst = (nfloat4*)(out + (size_t)cell * C_ + c);
    __builtin_nontemporal_store(mv, dst);
}

extern "C" void kernel_launch(void* const* d_in, const int* in_sizes, int n_in,
                              void* d_out, int out_size, void* d_ws, size_t ws_size,
                              hipStream_t stream) {
    const float* fm   = (const float*)d_in[0];
    const float* rois = (const float*)d_in[1];
    float* out        = (float*)d_out;

    const int nblocks = (B_ * R_ * PH * PW) / 4;  // 2450 blocks x 4 waves = 9800 waves
    ROIPoolingLayer_33071248179308_kernel<<<nblocks, 256, 0, stream>>>(fm, rois, out);
}